// Round 1
// baseline (200.512 us; speedup 1.0000x reference)
//
#include <hip/hip_runtime.h>
#include <stdint.h>

typedef __attribute__((ext_vector_type(4))) float f32x4;
typedef __attribute__((ext_vector_type(8))) __bf16 bf16x8;

#define MFMA16(a, b, c) __builtin_amdgcn_mfma_f32_16x16x32_bf16(a, b, c, 0, 0, 0)

static __device__ __forceinline__ unsigned short f2b(float f) {
  unsigned int u = __float_as_uint(f);
  u += 0x7fff + ((u >> 16) & 1);
  return (unsigned short)(u >> 16);
}

// ---------------------------------------------------------------- sizes
#define NROWS 8192
#define DIN   1024
#define DH    128
#define DOUT  1024

// ---------------------------------------------------------------- k1: weights -> bf16, transposed
__global__ void k_convert_w(const float* __restrict__ wqkv, const float* __restrict__ wout,
                            unsigned short* __restrict__ wqkvT, unsigned short* __restrict__ woutT) {
  int idx = blockIdx.x * 256 + threadIdx.x;
  if (idx < 384 * 1024) {                 // wqkvT [384][1024]: wqkvT[n][k] = wqkv[k][n]
    int n = idx >> 10, k = idx & 1023;
    wqkvT[idx] = f2b(wqkv[k * 384 + n]);
  }
  int idx2 = idx - 384 * 1024;
  if (idx2 >= 0 && idx2 < 1024 * 128) {   // woutT [1024][128]: woutT[n][k] = wout[k][n]
    int n = idx2 >> 7, k = idx2 & 127;
    woutT[idx2] = f2b(wout[k * 1024 + n]);
  }
}

// ---------------------------------------------------------------- k2: qkv GEMM (x f32 @ wqkvT bf16 -> Q/K/V bf16)
__launch_bounds__(256, 2)
__global__ void k_qkv_gemm(const float* __restrict__ x, const unsigned short* __restrict__ wT,
                           const float* __restrict__ bqkv,
                           unsigned short* __restrict__ Qb, unsigned short* __restrict__ Kb,
                           unsigned short* __restrict__ Vb) {
  const int bn = blockIdx.x;        // 0..2 -> Q/K/V column block
  const int bm = blockIdx.y;        // 0..63
  const int tid = threadIdx.x;
  const int lane = tid & 63, w = tid >> 6;
  const int l15 = lane & 15, g = lane >> 4;
  const int wm = (w >> 1) * 64, wn = (w & 1) * 64;
  const int row0 = bm * 128, ncol0 = bn * 128;

  __shared__ __align__(16) char Ash[8192];   // [128 m][32 k] bf16, 64B rows, swz
  __shared__ __align__(16) char Bsh[8192];   // [128 n][32 k] bf16 (w^T), swz

  f32x4 acc[4][4] = {};

  for (int k0 = 0; k0 < DIN; k0 += 32) {
    // stage A (f32 -> bf16): 128x32 = 1024 float4 chunks
#pragma unroll
    for (int j = 0; j < 4; ++j) {
      int c = j * 256 + tid;
      int r = c >> 3, kk = (c & 7) * 4;
      float4 v = *reinterpret_cast<const float4*>(x + (size_t)(row0 + r) * DIN + k0 + kk);
      ushort4 h;
      h.x = f2b(v.x); h.y = f2b(v.y); h.z = f2b(v.z); h.w = f2b(v.w);
      int byte = r * 64 + kk * 2;
      byte ^= (r & 7) << 4;
      *reinterpret_cast<ushort4*>(Ash + byte) = h;
    }
    // stage B^T (already bf16): 128x32 bf16 = 512 x 16B chunks
#pragma unroll
    for (int j = 0; j < 2; ++j) {
      int c = j * 256 + tid;
      int r = c >> 2, kk = (c & 3) * 8;
      uint4 v = *reinterpret_cast<const uint4*>(wT + (size_t)(ncol0 + r) * DIN + k0 + kk);
      int byte = r * 64 + kk * 2;
      byte ^= (r & 7) << 4;
      *reinterpret_cast<uint4*>(Bsh + byte) = v;
    }
    __syncthreads();

    bf16x8 af[4], bf[4];
#pragma unroll
    for (int i = 0; i < 4; ++i) {
      int r = wm + i * 16 + l15;
      int ba = r * 64 + g * 16;
      af[i] = *reinterpret_cast<bf16x8*>(Ash + (ba ^ ((r & 7) << 4)));
      int n = wn + i * 16 + l15;
      int bb = n * 64 + g * 16;
      bf[i] = *reinterpret_cast<bf16x8*>(Bsh + (bb ^ ((n & 7) << 4)));
    }
#pragma unroll
    for (int i = 0; i < 4; ++i)
#pragma unroll
      for (int jn = 0; jn < 4; ++jn)
        acc[i][jn] = MFMA16(af[i], bf[jn], acc[i][jn]);
    __syncthreads();
  }

  unsigned short* outb = (bn == 0) ? Qb : (bn == 1 ? Kb : Vb);
#pragma unroll
  for (int i = 0; i < 4; ++i)
#pragma unroll
    for (int jn = 0; jn < 4; ++jn)
#pragma unroll
      for (int r = 0; r < 4; ++r) {
        int grow = row0 + wm + i * 16 + g * 4 + r;
        int gcol = wn + jn * 16 + l15;          // 0..127 inside this buffer
        float vv = acc[i][jn][r] + bqkv[ncol0 + gcol];
        outb[(size_t)grow * DH + gcol] = f2b(vv);
      }
}

// ---------------------------------------------------------------- k3: V [8192][128] -> V^T [128][8192]
__global__ void k_transpose_v(const unsigned short* __restrict__ V, unsigned short* __restrict__ VT) {
  __shared__ __align__(16) unsigned short t[64 * 128];   // rotate-swizzled
  const int b = blockIdx.x;       // 64-row slab
  const int tid = threadIdx.x;
  const int kv0 = b * 64;
  // load coalesced, store with per-8-row rotation: elem (r,d) at col (d + ((r>>3)&7)*8) & 127
#pragma unroll
  for (int j = 0; j < 4; ++j) {
    int c = j * 256 + tid;
    int r = c >> 4, cc = (c & 15) * 8;
    uint4 v = *reinterpret_cast<const uint4*>(V + (size_t)(kv0 + r) * DH + cc);
    int col = (cc + ((r >> 3) & 7) * 8) & 127;
    *reinterpret_cast<uint4*>(&t[r * 128 + col]) = v;
  }
  __syncthreads();
#pragma unroll
  for (int j = 0; j < 4; ++j) {
    int c = j * 256 + tid;
    int d = c >> 3, kk = (c & 7) * 8;
    unsigned short tmp[8];
#pragma unroll
    for (int e = 0; e < 8; ++e) {
      int r = kk + e;
      int col = (d + ((r >> 3) & 7) * 8) & 127;
      tmp[e] = t[r * 128 + col];
    }
    *reinterpret_cast<uint4*>(VT + (size_t)d * NROWS + kv0 + kk) = *reinterpret_cast<uint4*>(tmp);
  }
}

// ---------------------------------------------------------------- k4: causal flash attention (chunked KV split)
#define KVCHUNK 2048
__launch_bounds__(256, 2)
__global__ void k_flash(const unsigned short* __restrict__ Q, const unsigned short* __restrict__ Kg,
                        const unsigned short* __restrict__ VT,
                        float* __restrict__ Opart, float* __restrict__ MLpart) {
  const int t = blockIdx.x;           // q tile (64 rows), 0..127
  const int ci = blockIdx.y;          // kv chunk, 0..3
  const int qb = t * 64;
  const int E = qb + 64;              // causal kv extent for this tile
  const int ks = ci * KVCHUNK;
  const int ke = min(ks + KVCHUNK, E);
  if (ks >= E) return;

  const int tid = threadIdx.x;
  const int lane = tid & 63, w = tid >> 6;
  const int l15 = lane & 15, g = lane >> 4;

  __shared__ __align__(16) char Ksh[16384];      // K [64][128] bf16, swz
  __shared__ __align__(16) char Vsh[16384];      // V^T [128][64] bf16, swz
  __shared__ __align__(16) char Psh[4][2048];    // per-wave P [16][64] bf16, swz

  // Q fragments (A operand), held in registers for the whole kernel
  const int qrow = qb + w * 16 + l15;
  bf16x8 qf[4];
#pragma unroll
  for (int d = 0; d < 4; ++d)
    qf[d] = *reinterpret_cast<const bf16x8*>(Q + (size_t)qrow * DH + d * 32 + g * 8);

  f32x4 acco[8] = {};
  float m[4], l[4];
#pragma unroll
  for (int r = 0; r < 4; ++r) { m[r] = -1e10f; l[r] = 0.f; }
  const float scale = 0.08838834764831843f;   // 128^-0.5
  const int myrow = qb + w * 16 + g * 4;

  const int nsteps = (ke - ks) >> 6;
  for (int s = 0; s < nsteps; ++s) {
    const int kv0 = ks + s * 64;
    // stage K: 64x128 bf16 = 1024 x 16B
#pragma unroll
    for (int j = 0; j < 4; ++j) {
      int c = j * 256 + tid;
      int r = c >> 4, cc = (c & 15) * 16;
      uint4 v = *reinterpret_cast<const uint4*>(Kg + (size_t)(kv0 + r) * DH + (cc >> 1));
      int byte = r * 256 + cc; byte ^= (r & 7) << 4;
      *reinterpret_cast<uint4*>(Ksh + byte) = v;
    }
    // stage V^T: 128 rows x 64 kv
#pragma unroll
    for (int j = 0; j < 4; ++j) {
      int c = j * 256 + tid;
      int d = c >> 3, cc = (c & 7) * 16;
      uint4 v = *reinterpret_cast<const uint4*>(VT + (size_t)d * NROWS + kv0 + (cc >> 1));
      int byte = d * 128 + cc; byte ^= (d & 7) << 4;
      *reinterpret_cast<uint4*>(Vsh + byte) = v;
    }
    __syncthreads();

    // QK^T: S [16 q][64 kv] per wave
    f32x4 accs[4] = {};
#pragma unroll
    for (int jc = 0; jc < 4; ++jc) {
#pragma unroll
      for (int d = 0; d < 4; ++d) {
        int r = jc * 16 + l15;
        int byte = r * 256 + d * 64 + g * 16; byte ^= (r & 7) << 4;
        bf16x8 bk = *reinterpret_cast<bf16x8*>(Ksh + byte);
        accs[jc] = MFMA16(qf[d], bk, accs[jc]);
      }
    }

    // scale + causal mask + online softmax
    float p[4][4];
#pragma unroll
    for (int jc = 0; jc < 4; ++jc)
#pragma unroll
      for (int r = 0; r < 4; ++r) {
        float sv = accs[jc][r] * scale;
        int col = kv0 + jc * 16 + l15;
        if (col > myrow + r) sv = -1e10f;
        p[jc][r] = sv;
      }
    float fac[4];
#pragma unroll
    for (int r = 0; r < 4; ++r) {
      float mx = fmaxf(fmaxf(p[0][r], p[1][r]), fmaxf(p[2][r], p[3][r]));
      mx = fmaxf(mx, __shfl_xor(mx, 1));
      mx = fmaxf(mx, __shfl_xor(mx, 2));
      mx = fmaxf(mx, __shfl_xor(mx, 4));
      mx = fmaxf(mx, __shfl_xor(mx, 8));
      float mnew = fmaxf(m[r], mx);
      fac[r] = __expf(m[r] - mnew);
      float ps = 0.f;
#pragma unroll
      for (int jc = 0; jc < 4; ++jc) {
        float e = __expf(p[jc][r] - mnew);
        p[jc][r] = e; ps += e;
      }
      ps += __shfl_xor(ps, 1);
      ps += __shfl_xor(ps, 2);
      ps += __shfl_xor(ps, 4);
      ps += __shfl_xor(ps, 8);
      l[r] = l[r] * fac[r] + ps;
      m[r] = mnew;
    }
#pragma unroll
    for (int dc = 0; dc < 8; ++dc)
#pragma unroll
      for (int r = 0; r < 4; ++r) acco[dc][r] *= fac[r];

    // P -> per-wave LDS (bf16, swizzled), then PV
    char* Pw = Psh[w];
#pragma unroll
    for (int jc = 0; jc < 4; ++jc)
#pragma unroll
      for (int r = 0; r < 4; ++r) {
        int row = g * 4 + r, col = jc * 16 + l15;
        int byte = row * 128 + col * 2; byte ^= (row & 7) << 4;
        *reinterpret_cast<unsigned short*>(Pw + byte) = f2b(p[jc][r]);
      }
    __asm__ volatile("s_waitcnt lgkmcnt(0)" ::: "memory");

    bf16x8 pf[2];
#pragma unroll
    for (int kslice = 0; kslice < 2; ++kslice) {
      int byte = l15 * 128 + kslice * 64 + g * 16; byte ^= (l15 & 7) << 4;
      pf[kslice] = *reinterpret_cast<bf16x8*>(Pw + byte);
    }
#pragma unroll
    for (int dc = 0; dc < 8; ++dc) {
#pragma unroll
      for (int kslice = 0; kslice < 2; ++kslice) {
        int vr = dc * 16 + l15;
        int byte = vr * 128 + kslice * 64 + g * 16; byte ^= (vr & 7) << 4;
        bf16x8 vf = *reinterpret_cast<bf16x8*>(Vsh + byte);
        acco[dc] = MFMA16(pf[kslice], vf, acco[dc]);
      }
    }
    __syncthreads();
  }

  // write partials
  const int base_row = qb + w * 16 + g * 4;
#pragma unroll
  for (int dc = 0; dc < 8; ++dc)
#pragma unroll
    for (int r = 0; r < 4; ++r)
      Opart[((size_t)ci * NROWS + base_row + r) * DH + dc * 16 + l15] = acco[dc][r];
  if (l15 == 0) {
#pragma unroll
    for (int r = 0; r < 4; ++r) {
      MLpart[((size_t)ci * NROWS + base_row + r) * 2 + 0] = m[r];
      MLpart[((size_t)ci * NROWS + base_row + r) * 2 + 1] = l[r];
    }
  }
}

// ---------------------------------------------------------------- k5: merge chunk partials -> O bf16
__global__ void k_merge(const float* __restrict__ Opart, const float* __restrict__ MLpart,
                        unsigned short* __restrict__ O) {
  int idx = blockIdx.x * 256 + threadIdx.x;    // over 8192*128
  int row = idx >> 7, d = idx & 127;
  int nc = (row >> 11) + 1;                    // valid chunks for this row
  float M = -3e38f;
  for (int i = 0; i < nc; ++i) M = fmaxf(M, MLpart[((size_t)i * NROWS + row) * 2]);
  float L = 0.f, acc = 0.f;
  for (int i = 0; i < nc; ++i) {
    float mi = MLpart[((size_t)i * NROWS + row) * 2];
    float li = MLpart[((size_t)i * NROWS + row) * 2 + 1];
    float wg = __expf(mi - M);
    L += li * wg;
    acc += wg * Opart[((size_t)i * NROWS + row) * DH + d];
  }
  O[idx] = f2b(acc / L);
}

// ---------------------------------------------------------------- k6: out GEMM (O bf16 @ woutT bf16 + b -> f32)
__launch_bounds__(256, 2)
__global__ void k_out_gemm(const unsigned short* __restrict__ O, const unsigned short* __restrict__ wT,
                           const float* __restrict__ bout, float* __restrict__ out) {
  const int bn = blockIdx.x;          // 0..7
  const int bm = blockIdx.y;          // 0..63
  const int tid = threadIdx.x;
  const int lane = tid & 63, w = tid >> 6;
  const int l15 = lane & 15, g = lane >> 4;
  const int wm = (w >> 1) * 64, wn = (w & 1) * 64;
  const int row0 = bm * 128, col0 = bn * 128;

  __shared__ __align__(16) char Ash[16384];   // [128 m][64 k] bf16, swz
  __shared__ __align__(16) char Bsh[16384];   // [128 n][64 k] bf16, swz

  f32x4 acc[4][4] = {};

  for (int k0 = 0; k0 < DH; k0 += 64) {
#pragma unroll
    for (int j = 0; j < 4; ++j) {
      int c = j * 256 + tid;
      int r = c >> 3, cc = (c & 7) * 16;
      uint4 va = *reinterpret_cast<const uint4*>(O + (size_t)(row0 + r) * DH + k0 + (cc >> 1));
      uint4 vb = *reinterpret_cast<const uint4*>(wT + (size_t)(col0 + r) * DH + k0 + (cc >> 1));
      int byte = r * 128 + cc; byte ^= (r & 7) << 4;
      *reinterpret_cast<uint4*>(Ash + byte) = va;
      *reinterpret_cast<uint4*>(Bsh + byte) = vb;
    }
    __syncthreads();
#pragma unroll
    for (int ksl = 0; ksl < 2; ++ksl) {
      bf16x8 af[4], bf[4];
#pragma unroll
      for (int i = 0; i < 4; ++i) {
        int r = wm + i * 16 + l15;
        int ba = r * 128 + ksl * 64 + g * 16;
        af[i] = *reinterpret_cast<bf16x8*>(Ash + (ba ^ ((r & 7) << 4)));
        int n = wn + i * 16 + l15;
        int bb = n * 128 + ksl * 64 + g * 16;
        bf[i] = *reinterpret_cast<bf16x8*>(Bsh + (bb ^ ((n & 7) << 4)));
      }
#pragma unroll
      for (int i = 0; i < 4; ++i)
#pragma unroll
        for (int jn = 0; jn < 4; ++jn)
          acc[i][jn] = MFMA16(af[i], bf[jn], acc[i][jn]);
    }
    __syncthreads();
  }
#pragma unroll
  for (int i = 0; i < 4; ++i)
#pragma unroll
    for (int jn = 0; jn < 4; ++jn)
#pragma unroll
      for (int r = 0; r < 4; ++r) {
        int grow = row0 + wm + i * 16 + g * 4 + r;
        int gcol = col0 + wn + jn * 16 + l15;
        out[(size_t)grow * DOUT + gcol] = acc[i][jn][r] + bout[gcol];
      }
}

// ---------------------------------------------------------------- launch
extern "C" void kernel_launch(void* const* d_in, const int* in_sizes, int n_in,
                              void* d_out, int out_size, void* d_ws, size_t ws_size,
                              hipStream_t stream) {
  const float* x    = (const float*)d_in[0];
  const float* wqkv = (const float*)d_in[1];
  const float* bqkv = (const float*)d_in[2];
  const float* wout = (const float*)d_in[3];
  const float* bout = (const float*)d_in[4];
  float* out = (float*)d_out;

  char* ws = (char*)d_ws;
  size_t off = 0;
  unsigned short* wqkvT = (unsigned short*)(ws + off); off += (size_t)384 * 1024 * 2;   // 786432
  unsigned short* woutT = (unsigned short*)(ws + off); off += (size_t)1024 * 128 * 2;   // 262144
  unsigned short* Qb = (unsigned short*)(ws + off); off += (size_t)NROWS * DH * 2;
  unsigned short* Kb = (unsigned short*)(ws + off); off += (size_t)NROWS * DH * 2;
  unsigned short* Vb = (unsigned short*)(ws + off); off += (size_t)NROWS * DH * 2;
  unsigned short* VTb = (unsigned short*)(ws + off); off += (size_t)NROWS * DH * 2;
  unsigned short* Ob = (unsigned short*)(ws + off); off += (size_t)NROWS * DH * 2;
  float* Opart = (float*)(ws + off); off += (size_t)4 * NROWS * DH * 4;                 // 16 MB
  float* MLpart = (float*)(ws + off); off += (size_t)4 * NROWS * 2 * 4;

  k_convert_w<<<2048, 256, 0, stream>>>(wqkv, wout, wqkvT, woutT);
  k_qkv_gemm<<<dim3(3, 64), 256, 0, stream>>>(x, wqkvT, bqkv, Qb, Kb, Vb);
  k_transpose_v<<<128, 256, 0, stream>>>(Vb, VTb);
  k_flash<<<dim3(128, 4), 256, 0, stream>>>(Qb, Kb, VTb, Opart, MLpart);
  k_merge<<<(NROWS * DH) / 256, 256, 0, stream>>>(Opart, MLpart, Ob);
  k_out_gemm<<<dim3(8, 64), 256, 0, stream>>>(Ob, woutT, bout, out);
}

// Round 2
// 150.827 us; speedup vs baseline: 1.3294x; 1.3294x over previous
//
#include <hip/hip_runtime.h>
#include <stdint.h>

typedef __attribute__((ext_vector_type(4))) float f32x4;
typedef __attribute__((ext_vector_type(8))) __bf16 bf16x8;

#define MFMA16(a, b, c) __builtin_amdgcn_mfma_f32_16x16x32_bf16(a, b, c, 0, 0, 0)
#define GLOAD16(g, l)                                                              \
  __builtin_amdgcn_global_load_lds(                                                \
      (const __attribute__((address_space(1))) unsigned int*)(g),                  \
      (__attribute__((address_space(3))) unsigned int*)(l), 16, 0, 0)

static __device__ __forceinline__ unsigned short f2b(float f) {
  unsigned int u = __float_as_uint(f);
  u += 0x7fff + ((u >> 16) & 1);
  return (unsigned short)(u >> 16);
}

// ---------------------------------------------------------------- sizes
#define NROWS 8192
#define DIN   1024
#define DH    128
#define DOUT  1024

// ---------------------------------------------------------------- k1: weights -> bf16, transposed
__global__ void k_convert_w(const float* __restrict__ wqkv, const float* __restrict__ wout,
                            unsigned short* __restrict__ wqkvT, unsigned short* __restrict__ woutT) {
  int idx = blockIdx.x * 256 + threadIdx.x;
  if (idx < 384 * 1024) {                 // wqkvT [384][1024]: wqkvT[n][k] = wqkv[k][n]
    int n = idx >> 10, k = idx & 1023;
    wqkvT[idx] = f2b(wqkv[k * 384 + n]);
  }
  int idx2 = idx - 384 * 1024;
  if (idx2 >= 0 && idx2 < 1024 * 128) {   // woutT [1024][128]: woutT[n][k] = wout[k][n]
    int n = idx2 >> 7, k = idx2 & 127;
    woutT[idx2] = f2b(wout[k * 1024 + n]);
  }
}

// ---------------------------------------------------------------- k1b: x -> bf16
__global__ void k_convert_x(const float* __restrict__ x, unsigned short* __restrict__ xb) {
  int i = (blockIdx.x * 256 + threadIdx.x) * 4;
  float4 v = *reinterpret_cast<const float4*>(x + i);
  ushort4 h;
  h.x = f2b(v.x); h.y = f2b(v.y); h.z = f2b(v.z); h.w = f2b(v.w);
  *reinterpret_cast<ushort4*>(xb + i) = h;
}

// ---------------------------------------------------------------- k2: qkv GEMM (xb bf16 @ wqkvT bf16 -> Q/K/V bf16)
// 64x64 tiles, grid (6,128) = 768 blocks
__launch_bounds__(256, 2)
__global__ void k_qkv_gemm(const unsigned short* __restrict__ xb, const unsigned short* __restrict__ wT,
                           const float* __restrict__ bqkv,
                           unsigned short* __restrict__ Qb, unsigned short* __restrict__ Kb,
                           unsigned short* __restrict__ Vb) {
  const int bn = blockIdx.x;        // 0..5 -> 64-col tile of [Q|K|V]
  const int bm = blockIdx.y;        // 0..127
  const int tid = threadIdx.x;
  const int lane = tid & 63, w = tid >> 6;
  const int l15 = lane & 15, g = lane >> 4;
  const int wm = (w >> 1) * 32, wn = (w & 1) * 32;
  const int row0 = bm * 64, ncol0 = bn * 64;

  __shared__ __align__(16) char Ash[8192];   // [64 m][64 k] bf16, 128B rows, swz
  __shared__ __align__(16) char Bsh[8192];   // [64 n][64 k] bf16, swz

  f32x4 acc[2][2] = {};

  for (int k0 = 0; k0 < DIN; k0 += 64) {
#pragma unroll
    for (int j = 0; j < 2; ++j) {
      int idx = j * 256 + tid;
      int r = idx >> 3, gg = idx & 7;
      int sgg = gg ^ (r & 7);                 // pre-swizzled source granule
      GLOAD16(xb + (size_t)(row0 + r) * DIN + k0 + sgg * 8, Ash + idx * 16);
      GLOAD16(wT + (size_t)(ncol0 + r) * DIN + k0 + sgg * 8, Bsh + idx * 16);
    }
    __syncthreads();
#pragma unroll
    for (int ksl = 0; ksl < 2; ++ksl) {
      bf16x8 af[2], bfr[2];
#pragma unroll
      for (int i = 0; i < 2; ++i) {
        int r = wm + i * 16 + l15;
        int ba = r * 128 + ksl * 64 + g * 16;
        af[i] = *reinterpret_cast<bf16x8*>(Ash + (ba ^ ((r & 7) << 4)));
        int n = wn + i * 16 + l15;
        int bb = n * 128 + ksl * 64 + g * 16;
        bfr[i] = *reinterpret_cast<bf16x8*>(Bsh + (bb ^ ((n & 7) << 4)));
      }
#pragma unroll
      for (int i = 0; i < 2; ++i)
#pragma unroll
        for (int jn = 0; jn < 2; ++jn)
          acc[i][jn] = MFMA16(af[i], bfr[jn], acc[i][jn]);
    }
    __syncthreads();
  }

  const int which = ncol0 >> 7;
  unsigned short* outb = (which == 0) ? Qb : (which == 1 ? Kb : Vb);
#pragma unroll
  for (int i = 0; i < 2; ++i)
#pragma unroll
    for (int jn = 0; jn < 2; ++jn)
#pragma unroll
      for (int r = 0; r < 4; ++r) {
        int grow = row0 + wm + i * 16 + g * 4 + r;
        int lcol = wn + jn * 16 + l15;                    // 0..63
        float vv = acc[i][jn][r] + bqkv[ncol0 + lcol];
        outb[(size_t)grow * DH + ((ncol0 & 64) + lcol)] = f2b(vv);
      }
}

// ---------------------------------------------------------------- k3: V [8192][128] -> V^T [128][8192]
__global__ void k_transpose_v(const unsigned short* __restrict__ V, unsigned short* __restrict__ VT) {
  __shared__ __align__(16) unsigned short t[64 * 128];   // rotate-swizzled
  const int b = blockIdx.x;       // 64-row slab
  const int tid = threadIdx.x;
  const int kv0 = b * 64;
#pragma unroll
  for (int j = 0; j < 4; ++j) {
    int c = j * 256 + tid;
    int r = c >> 4, cc = (c & 15) * 8;
    uint4 v = *reinterpret_cast<const uint4*>(V + (size_t)(kv0 + r) * DH + cc);
    int col = (cc + ((r >> 3) & 7) * 8) & 127;
    *reinterpret_cast<uint4*>(&t[r * 128 + col]) = v;
  }
  __syncthreads();
#pragma unroll
  for (int j = 0; j < 4; ++j) {
    int c = j * 256 + tid;
    int d = c >> 3, kk = (c & 7) * 8;
    unsigned short tmp[8];
#pragma unroll
    for (int e = 0; e < 8; ++e) {
      int r = kk + e;
      int col = (d + ((r >> 3) & 7) * 8) & 127;
      tmp[e] = t[r * 128 + col];
    }
    *reinterpret_cast<uint4*>(VT + (size_t)d * NROWS + kv0 + kk) = *reinterpret_cast<uint4*>(tmp);
  }
}

// ---------------------------------------------------------------- k4: causal flash attention, balanced KV chunks
// grid (128>>LJ, 128); chunk = J*64 kv; compact partial slots
__launch_bounds__(256, 2)
__global__ void k_flash(const unsigned short* __restrict__ Q, const unsigned short* __restrict__ Kg,
                        const unsigned short* __restrict__ VT,
                        float* __restrict__ Opart, float* __restrict__ MLpart, int LJ) {
  const int ci = blockIdx.x;
  const int t = blockIdx.y;
  const int J = 1 << LJ;
  if (ci * J > t) return;                       // chunk start >= causal extent
  const int qb = t * 64;
  const int E = qb + 64;
  const int ks = ci * (J << 6);
  const int ke = min(ks + (J << 6), E);

  // compact slot index
  const int a = t >> LJ, b = t & (J - 1);
  const int slot = t + ((J * a * (a - 1)) >> 1) + a * b + ci;

  const int tid = threadIdx.x;
  const int lane = tid & 63, w = tid >> 6;
  const int l15 = lane & 15, g = lane >> 4;

  __shared__ __align__(16) char Ksh[16384];      // K [64][128] bf16, swz
  __shared__ __align__(16) char Vsh[16384];      // V^T [128][64] bf16, swz
  __shared__ __align__(16) char Psh[4][2048];    // per-wave P [16][64] bf16, swz

  const int qrow = qb + w * 16 + l15;
  bf16x8 qf[4];
#pragma unroll
  for (int d = 0; d < 4; ++d)
    qf[d] = *reinterpret_cast<const bf16x8*>(Q + (size_t)qrow * DH + d * 32 + g * 8);

  f32x4 acco[8] = {};
  float m[4], l[4];
#pragma unroll
  for (int r = 0; r < 4; ++r) { m[r] = -1e10f; l[r] = 0.f; }
  const float scale = 0.08838834764831843f;   // 128^-0.5
  const int myrow = qb + w * 16 + g * 4;

  const int nsteps = (ke - ks) >> 6;
  for (int s = 0; s < nsteps; ++s) {
    const int kv0 = ks + s * 64;
    // stage K via global_load_lds, pre-swizzled source (LDS stays lane-linear)
#pragma unroll
    for (int j = 0; j < 4; ++j) {
      int idx = j * 256 + tid;
      int r = idx >> 4, gg = idx & 15;
      int sgg = gg ^ (r & 7);
      GLOAD16(Kg + (size_t)(kv0 + r) * DH + sgg * 8, Ksh + idx * 16);
    }
    // stage V^T
#pragma unroll
    for (int j = 0; j < 4; ++j) {
      int idx = j * 256 + tid;
      int d = idx >> 3, gg = idx & 7;
      int sgg = gg ^ (d & 7);
      GLOAD16(VT + (size_t)d * NROWS + kv0 + sgg * 8, Vsh + idx * 16);
    }
    __syncthreads();

    // QK^T: S [16 q][64 kv] per wave
    f32x4 accs[4] = {};
#pragma unroll
    for (int jc = 0; jc < 4; ++jc) {
#pragma unroll
      for (int d = 0; d < 4; ++d) {
        int r = jc * 16 + l15;
        int byte = r * 256 + d * 64 + g * 16; byte ^= (r & 7) << 4;
        bf16x8 bk = *reinterpret_cast<bf16x8*>(Ksh + byte);
        accs[jc] = MFMA16(qf[d], bk, accs[jc]);
      }
    }

    // scale + causal mask + online softmax
    float p[4][4];
#pragma unroll
    for (int jc = 0; jc < 4; ++jc)
#pragma unroll
      for (int r = 0; r < 4; ++r) {
        float sv = accs[jc][r] * scale;
        int col = kv0 + jc * 16 + l15;
        if (col > myrow + r) sv = -1e10f;
        p[jc][r] = sv;
      }
    float fac[4];
#pragma unroll
    for (int r = 0; r < 4; ++r) {
      float mx = fmaxf(fmaxf(p[0][r], p[1][r]), fmaxf(p[2][r], p[3][r]));
      mx = fmaxf(mx, __shfl_xor(mx, 1));
      mx = fmaxf(mx, __shfl_xor(mx, 2));
      mx = fmaxf(mx, __shfl_xor(mx, 4));
      mx = fmaxf(mx, __shfl_xor(mx, 8));
      float mnew = fmaxf(m[r], mx);
      fac[r] = __expf(m[r] - mnew);
      float ps = 0.f;
#pragma unroll
      for (int jc = 0; jc < 4; ++jc) {
        float e = __expf(p[jc][r] - mnew);
        p[jc][r] = e; ps += e;
      }
      ps += __shfl_xor(ps, 1);
      ps += __shfl_xor(ps, 2);
      ps += __shfl_xor(ps, 4);
      ps += __shfl_xor(ps, 8);
      l[r] = l[r] * fac[r] + ps;
      m[r] = mnew;
    }
#pragma unroll
    for (int dc = 0; dc < 8; ++dc)
#pragma unroll
      for (int r = 0; r < 4; ++r) acco[dc][r] *= fac[r];

    // P -> per-wave LDS (bf16, swizzled), then PV
    char* Pw = Psh[w];
#pragma unroll
    for (int jc = 0; jc < 4; ++jc)
#pragma unroll
      for (int r = 0; r < 4; ++r) {
        int row = g * 4 + r, col = jc * 16 + l15;
        int byte = row * 128 + col * 2; byte ^= (row & 7) << 4;
        *reinterpret_cast<unsigned short*>(Pw + byte) = f2b(p[jc][r]);
      }
    __asm__ volatile("s_waitcnt lgkmcnt(0)" ::: "memory");

    bf16x8 pf[2];
#pragma unroll
    for (int kslice = 0; kslice < 2; ++kslice) {
      int byte = l15 * 128 + kslice * 64 + g * 16; byte ^= (l15 & 7) << 4;
      pf[kslice] = *reinterpret_cast<bf16x8*>(Pw + byte);
    }
#pragma unroll
    for (int dc = 0; dc < 8; ++dc) {
#pragma unroll
      for (int kslice = 0; kslice < 2; ++kslice) {
        int vr = dc * 16 + l15;
        int byte = vr * 128 + kslice * 64 + g * 16; byte ^= (vr & 7) << 4;
        bf16x8 vf = *reinterpret_cast<bf16x8*>(Vsh + byte);
        acco[dc] = MFMA16(pf[kslice], vf, acco[dc]);
      }
    }
    __syncthreads();
  }

  // write partials (compact slot layout)
  const int lr = w * 16 + g * 4;
#pragma unroll
  for (int dc = 0; dc < 8; ++dc)
#pragma unroll
    for (int r = 0; r < 4; ++r)
      Opart[((size_t)slot * 64 + lr + r) * DH + dc * 16 + l15] = acco[dc][r];
  if (l15 == 0) {
#pragma unroll
    for (int r = 0; r < 4; ++r) {
      MLpart[((size_t)slot * 64 + lr + r) * 2 + 0] = m[r];
      MLpart[((size_t)slot * 64 + lr + r) * 2 + 1] = l[r];
    }
  }
}

// ---------------------------------------------------------------- k5: merge chunk partials -> O bf16
__global__ void k_merge(const float* __restrict__ Opart, const float* __restrict__ MLpart,
                        unsigned short* __restrict__ O, int LJ) {
  int idx = blockIdx.x * 256 + threadIdx.x;    // over 8192*128
  int row = idx >> 7, d = idx & 127;
  int t = row >> 6;
  int J = 1 << LJ;
  int a = t >> LJ, b = t & (J - 1);
  int base = t + ((J * a * (a - 1)) >> 1) + a * b;
  int nc = a + 1;
  float M = -3e38f;
  for (int i = 0; i < nc; ++i) M = fmaxf(M, MLpart[((size_t)(base + i) * 64 + (row & 63)) * 2]);
  float L = 0.f, acc = 0.f;
  for (int i = 0; i < nc; ++i) {
    size_t sr = (size_t)(base + i) * 64 + (row & 63);
    float mi = MLpart[sr * 2];
    float li = MLpart[sr * 2 + 1];
    float wg = __expf(mi - M);
    L += li * wg;
    acc += wg * Opart[sr * DH + d];
  }
  O[idx] = f2b(acc / L);
}

// ---------------------------------------------------------------- k6: out GEMM (Ob bf16 @ woutT bf16 + b -> f32)
// 64x64 tiles, K=128 single stage, grid (16,128) = 2048 blocks
__launch_bounds__(256, 2)
__global__ void k_out_gemm(const unsigned short* __restrict__ O, const unsigned short* __restrict__ wT,
                           const float* __restrict__ bout, float* __restrict__ out) {
  const int bn = blockIdx.x;          // 0..15
  const int bm = blockIdx.y;          // 0..127
  const int tid = threadIdx.x;
  const int lane = tid & 63, w = tid >> 6;
  const int l15 = lane & 15, g = lane >> 4;
  const int wm = (w >> 1) * 32, wn = (w & 1) * 32;
  const int row0 = bm * 64, col0 = bn * 64;

  __shared__ __align__(16) char Ash[16384];   // [64 m][128 k] bf16, 256B rows, swz
  __shared__ __align__(16) char Bsh[16384];   // [64 n][128 k] bf16, swz

#pragma unroll
  for (int j = 0; j < 4; ++j) {
    int idx = j * 256 + tid;
    int r = idx >> 4, gg = idx & 15;
    int sgg = gg ^ (r & 7);
    GLOAD16(O + (size_t)(row0 + r) * DH + sgg * 8, Ash + idx * 16);
    GLOAD16(wT + (size_t)(col0 + r) * DH + sgg * 8, Bsh + idx * 16);
  }
  __syncthreads();

  f32x4 acc[2][2] = {};
#pragma unroll
  for (int ksl = 0; ksl < 4; ++ksl) {
    bf16x8 af[2], bfr[2];
#pragma unroll
    for (int i = 0; i < 2; ++i) {
      int r = wm + i * 16 + l15;
      int ba = r * 256 + ksl * 64 + g * 16;
      af[i] = *reinterpret_cast<bf16x8*>(Ash + (ba ^ ((r & 7) << 4)));
      int n = wn + i * 16 + l15;
      int bb = n * 256 + ksl * 64 + g * 16;
      bfr[i] = *reinterpret_cast<bf16x8*>(Bsh + (bb ^ ((n & 7) << 4)));
    }
#pragma unroll
    for (int i = 0; i < 2; ++i)
#pragma unroll
      for (int jn = 0; jn < 2; ++jn)
        acc[i][jn] = MFMA16(af[i], bfr[jn], acc[i][jn]);
  }

#pragma unroll
  for (int i = 0; i < 2; ++i)
#pragma unroll
    for (int jn = 0; jn < 2; ++jn)
#pragma unroll
      for (int r = 0; r < 4; ++r) {
        int grow = row0 + wm + i * 16 + g * 4 + r;
        int gcol = col0 + wn + jn * 16 + l15;
        out[(size_t)grow * DOUT + gcol] = acc[i][jn][r] + bout[gcol];
      }
}

// ---------------------------------------------------------------- launch
extern "C" void kernel_launch(void* const* d_in, const int* in_sizes, int n_in,
                              void* d_out, int out_size, void* d_ws, size_t ws_size,
                              hipStream_t stream) {
  const float* x    = (const float*)d_in[0];
  const float* wqkv = (const float*)d_in[1];
  const float* bqkv = (const float*)d_in[2];
  const float* wout = (const float*)d_in[3];
  const float* bout = (const float*)d_in[4];
  float* out = (float*)d_out;

  // adaptive KV-chunk size: smallest J (most parallelism) whose partials fit ws
  size_t fixed = 786432 + 262144 + (size_t)NROWS * DIN * 2 + (size_t)5 * NROWS * DH * 2;
  int LJ = 3;
  size_t slots = 0;
  for (; LJ <= 7; ++LJ) {
    int J = 1 << LJ, A = 128 >> LJ;
    slots = 128 + (size_t)J * A * (A - 1) / 2;
    size_t need = fixed + slots * ((size_t)64 * DH * 4 + 64 * 8);
    if (need <= ws_size || LJ == 7) break;
  }

  char* ws = (char*)d_ws;
  size_t off = 0;
  unsigned short* wqkvT = (unsigned short*)(ws + off); off += (size_t)384 * 1024 * 2;
  unsigned short* woutT = (unsigned short*)(ws + off); off += (size_t)1024 * 128 * 2;
  unsigned short* xb  = (unsigned short*)(ws + off); off += (size_t)NROWS * DIN * 2;
  unsigned short* Qb  = (unsigned short*)(ws + off); off += (size_t)NROWS * DH * 2;
  unsigned short* Kb  = (unsigned short*)(ws + off); off += (size_t)NROWS * DH * 2;
  unsigned short* Vb  = (unsigned short*)(ws + off); off += (size_t)NROWS * DH * 2;
  unsigned short* VTb = (unsigned short*)(ws + off); off += (size_t)NROWS * DH * 2;
  unsigned short* Ob  = (unsigned short*)(ws + off); off += (size_t)NROWS * DH * 2;
  float* Opart  = (float*)(ws + off); off += slots * (size_t)64 * DH * 4;
  float* MLpart = (float*)(ws + off); off += slots * (size_t)64 * 8;

  k_convert_w<<<2048, 256, 0, stream>>>(wqkv, wout, wqkvT, woutT);
  k_convert_x<<<(NROWS * DIN) / 1024, 256, 0, stream>>>(x, xb);
  k_qkv_gemm<<<dim3(6, 128), 256, 0, stream>>>(xb, wqkvT, bqkv, Qb, Kb, Vb);
  k_transpose_v<<<128, 256, 0, stream>>>(Vb, VTb);
  k_flash<<<dim3(128 >> LJ, 128), 256, 0, stream>>>(Qb, Kb, VTb, Opart, MLpart, LJ);
  k_merge<<<(NROWS * DH) / 256, 256, 0, stream>>>(Opart, MLpart, Ob, LJ);
  k_out_gemm<<<dim3(16, 128), 256, 0, stream>>>(Ob, woutT, bout, out);
}